// Round 12
// baseline (308.391 us; speedup 1.0000x reference)
//
#include <hip/hip_runtime.h>
#include <hip/hip_fp16.h>
#include <stdint.h>

typedef _Float16 f16;
typedef _Float16 f16x4 __attribute__((ext_vector_type(4)));
typedef _Float16 f16x8 __attribute__((ext_vector_type(8)));
typedef float f32x4 __attribute__((ext_vector_type(4)));

#define T_STEPS 200
#define LOG2E 1.4426950408889634f
#define TWOLOG2E 2.8853900817779268f
#define GSTRIDE (512 * 512)   // f16 elements per time step of gi
#define OSTRIDE (512 * 256)   // f32 elements per time step of out
#define ATT_STRIDE 208        // floats per row in att_s

#define MFMA16(a,b,c) __builtin_amdgcn_mfma_f32_16x16x32_f16((a),(b),(c),0,0,0)

__device__ __forceinline__ f16x8 cvt_f16x8(const float4 lo, const float4 hi) {
  f16x8 f;
  f[0]=(f16)lo.x; f[1]=(f16)lo.y; f[2]=(f16)lo.z; f[3]=(f16)lo.w;
  f[4]=(f16)hi.x; f[5]=(f16)hi.y; f[6]=(f16)hi.z; f[7]=(f16)hi.w;
  return f;
}
__device__ __forceinline__ f16x4 cvt_f16x4v(const f32x4 v) {
  f16x4 f; f[0]=(f16)v[0]; f[1]=(f16)v[1]; f[2]=(f16)v[2]; f[3]=(f16)v[3]; return f;
}

// ---------------------------------------------------------------------------
// Kernel 1: gi stored f16 aliased into d_out, permuted so each gru thread
// reads ONE contiguous 16B chunk (8 f16: [gr e0..3, gn e0..3]) per step:
//   chunk addr (f16) = ((t*32 + blk)*16 + wv)*512 + (kq*16 + r)*8 + gate*4
// where blk = b>>4 (batch block), r = b&15, wv = j>>4, kq = (j>>2)&3, e = j&3.
//   gr pre-scaled by -log2e (sigmoid), gn pre-scaled by 2*log2e (tanh).
// W_ih rows: r gate = [0,256), n gate = [512,768)  (z gate unused).
// ---------------------------------------------------------------------------
__global__ __launch_bounds__(512, 2) void gi_kernel(
    const float* __restrict__ x,
    const int*   __restrict__ lengths,
    const float* __restrict__ w_ih,
    const float* __restrict__ b_ih,
    const float* __restrict__ b_hh,
    f16*         __restrict__ gi)
{
  const int m0 = blockIdx.x * 256;
  const int t  = m0 >> 9;
  const int bhalf = m0 & 511;          // 0 or 256
  if (t >= lengths[bhalf]) return;     // whole half-slice dead

  int nlive = 0;
  while (nlive < 16 && t < lengths[bhalf + nlive * 16]) ++nlive;

  __shared__ __align__(16) f16 xs[2][16 * 264];

  const int tid  = threadIdx.x;
  const int wave = tid >> 6;
  const int lane = tid & 63;
  const int cl   = lane & 15;
  const int kq   = lane >> 4;
  const int kk   = kq * 8;
  const float kscale = (wave < 4) ? -LOG2E : TWOLOG2E;

  f16x8 wf[4][8];
  float bias[4][4];
#pragma unroll
  for (int ct = 0; ct < 4; ++ct) {
    const int crow = wave * 64 + ct * 16 + cl;
    const int srow = (wave < 4) ? crow : (256 + crow);   // n gate rows 512+
    const float* p = w_ih + (size_t)srow * 256 + kk;
#pragma unroll
    for (int kt = 0; kt < 8; ++kt)
      wf[ct][kt] = cvt_f16x8(*(const float4*)(p + kt * 32),
                             *(const float4*)(p + kt * 32 + 4));
    const int cb = wave * 64 + ct * 16 + kq * 4;
    if (wave < 4) {
      float4 bi = *(const float4*)(b_ih + cb);
      float4 bh = *(const float4*)(b_hh + cb);
      bias[ct][0] = bi.x + bh.x; bias[ct][1] = bi.y + bh.y;
      bias[ct][2] = bi.z + bh.z; bias[ct][3] = bi.w + bh.w;
    } else {
      float4 bi = *(const float4*)(b_ih + 256 + cb);
      bias[ct][0] = bi.x; bias[ct][1] = bi.y;
      bias[ct][2] = bi.z; bias[ct][3] = bi.w;
    }
  }

  const int wv0   = (wave & 3) * 4;          // + ct
  const int gate4 = (wave >= 4) ? 4 : 0;

  f32x4 g[2];
#pragma unroll
  for (int i = 0; i < 2; ++i) {
    int q = i * 512 + tid; int r = q >> 6; int kc = (q & 63) * 4;
    g[i] = __builtin_nontemporal_load(
        (const f32x4*)(x + (size_t)(m0 + r) * 256 + kc));
  }
#pragma unroll
  for (int i = 0; i < 2; ++i) {
    int q = i * 512 + tid; int r = q >> 6; int kc = (q & 63) * 4;
    *(f16x4*)(&xs[0][r * 264 + kc]) = cvt_f16x4v(g[i]);
  }
  __syncthreads();

  for (int ms = 0; ms < nlive; ++ms) {
    const int buf = ms & 1;
    const bool more = (ms + 1) < nlive;
    if (more) {
#pragma unroll
      for (int i = 0; i < 2; ++i) {
        int q = i * 512 + tid; int r = q >> 6; int kc = (q & 63) * 4;
        g[i] = __builtin_nontemporal_load(
            (const f32x4*)(x + (size_t)(m0 + (ms + 1) * 16 + r) * 256 + kc));
      }
    }
    f32x4 acc[4];
#pragma unroll
    for (int ct = 0; ct < 4; ++ct) acc[ct] = (f32x4){0.f, 0.f, 0.f, 0.f};
#pragma unroll
    for (int kt = 0; kt < 8; ++kt) {
      f16x8 bx = *(const f16x8*)(&xs[buf][cl * 264 + kt * 32 + kk]);
#pragma unroll
      for (int ct = 0; ct < 4; ++ct)
        acc[ct] = MFMA16(wf[ct][kt], bx, acc[ct]);
    }
    const int blk = (bhalf >> 4) + ms;     // batch-block of 16 rows
    const size_t base = ((size_t)t * 32 + blk) * 8192
                      + (size_t)(kq * 16 + cl) * 8 + gate4;
#pragma unroll
    for (int ct = 0; ct < 4; ++ct) {
      f16x4 v;
#pragma unroll
      for (int e = 0; e < 4; ++e)
        v[e] = (f16)(kscale * (acc[ct][e] + bias[ct][e]));
      *(f16x4*)(gi + base + (size_t)(wv0 + ct) * 512) = v;
    }
    if (more) {
#pragma unroll
      for (int i = 0; i < 2; ++i) {
        int q = i * 512 + tid; int r = q >> 6; int kc = (q & 63) * 4;
        *(f16x4*)(&xs[buf ^ 1][r * 264 + kc]) = cvt_f16x4v(g[i]);
      }
    }
    __syncthreads();
  }
}

// ---------------------------------------------------------------------------
// Kernel 2: recurrence. 32 blocks x 16 rows, 16 waves (1024 thr, 4/SIMD).
// Round-10 structure + this round's changes:
//  - PLAIN out stores (nt removed: store acks at L2, not HBM -> vmcnt waits
//    placed by the compiler before next gi use no longer drag HBM store acks)
//  - distance-2 gi prefetch (4 rotating f16x8 sets, 4-body unroll)
//  - MFMA split into two depth-4 chains per gate (+add) to cut serial latency
//  - barrier remains lgkmcnt(0)-only (LDS h double-buffer is the only
//    cross-wave dependency)
// ---------------------------------------------------------------------------
#define GRU_BODY(T, HSR, HSW, Qu, Qd, AV)                                      \
  {                                                                            \
    const f16* gpe = (gp < gplim) ? gp : gplim;                                \
    Qd = *(const f16x8*)gpe;                                                   \
    gp += GSTRIDE;                                                             \
    f32x4 ar0 = (f32x4){0.f,0.f,0.f,0.f}, ar1 = ar0, an0 = ar0, an1 = ar0;     \
    _Pragma("unroll")                                                          \
    for (int kt = 0; kt < 4; ++kt) {                                           \
      f16x8 hf = *(const f16x8*)(&HSR[r * 264 + kt * 32 + kk]);                \
      ar0 = MFMA16(whr[kt], hf, ar0);                                          \
      an0 = MFMA16(whn[kt], hf, an0);                                          \
    }                                                                          \
    _Pragma("unroll")                                                          \
    for (int kt = 4; kt < 8; ++kt) {                                           \
      f16x8 hf = *(const f16x8*)(&HSR[r * 264 + kt * 32 + kk]);                \
      ar1 = MFMA16(whr[kt], hf, ar1);                                          \
      an1 = MFMA16(whn[kt], hf, an1);                                          \
    }                                                                          \
    const f32x4 ar = ar0 + ar1;                                                \
    const f32x4 an = an0 + an1;                                                \
    const bool live = (T) < len;                                               \
    const float Au = AV;                                                       \
    f32x4 sv; f16x4 hv;                                                        \
    _Pragma("unroll")                                                          \
    for (int e = 0; e < 4; ++e) {                                              \
      float gr  = (float)Qu[e];                                                \
      float gn  = (float)Qu[4 + e];                                            \
      float e2  = __builtin_amdgcn_exp2f(fmaf(ar[e], -LOG2E, gr));             \
      float rst = __builtin_amdgcn_rcpf(1.f + e2);                             \
      float hnv = fmaf(an[e], TWOLOG2E, bhn2[e]);                              \
      float q2  = fmaf(rst, hnv, gn);                                          \
      float en  = __builtin_amdgcn_exp2f(q2);                                  \
      float ns  = fmaf(-2.f, __builtin_amdgcn_rcpf(1.f + en), 1.f);            \
      float hy  = fmaf(Au, ns - hc[e], hc[e]);                                 \
      hc[e] = hy;                            /* att==0 past len -> frozen */   \
      sv[e] = live ? hy : 0.f;                                                 \
      hv[e] = (f16)hy;                                                         \
    }                                                                          \
    *(f32x4*)op = sv;                       /* plain store: acks at L2 */      \
    op += OSTRIDE;                                                             \
    *(f16x4*)(&HSW[r * 264 + jbase]) = hv;                                     \
    asm volatile("s_waitcnt lgkmcnt(0)" ::: "memory");                         \
    __builtin_amdgcn_s_barrier();                                              \
    __builtin_amdgcn_sched_barrier(0);                                         \
  }

__global__ __launch_bounds__(1024, 4) void gru_kernel(
    const float* __restrict__ att,
    const int*   __restrict__ lengths,
    const float* __restrict__ h0,
    const float* __restrict__ w_hh,
    const float* __restrict__ b_hh,
    float*       __restrict__ out)
{
  const f16* gi = (const f16*)out;   // aliased precomputed gi (permuted chunks)
  const int blk  = blockIdx.x;
  const int bb   = blk * 16;
  const int tid  = threadIdx.x;
  const int w    = tid >> 6;         // 0..15
  const int lane = tid & 63;
  const int r    = lane & 15;        // thread's batch row (local)
  const int kq   = lane >> 4;
  const int kk   = kq * 8;
  const int jbase = w * 16 + kq * 4; // thread's 4 output cols

  __shared__ __align__(16) f16   hs0[16 * 264];
  __shared__ __align__(16) f16   hs1[16 * 264];
  __shared__ __align__(16) float att_s[16 * ATT_STRIDE];   // [r][t]

  // resident W_hh A-frags: wave owns rows j = w*16+r (r-gate), 512+w*16+r (n)
  f16x8 whr[8], whn[8];
  {
    const int jrow = w * 16 + r;
    const float* pr = w_hh + (size_t)jrow * 256 + kk;
    const float* pn = w_hh + (size_t)(512 + jrow) * 256 + kk;
#pragma unroll
    for (int kt = 0; kt < 8; ++kt) {
      whr[kt] = cvt_f16x8(*(const float4*)(pr + kt * 32),
                          *(const float4*)(pr + kt * 32 + 4));
      whn[kt] = cvt_f16x8(*(const float4*)(pn + kt * 32),
                          *(const float4*)(pn + kt * 32 + 4));
    }
  }

  float bhn2[4];
  {
    float4 bn = *(const float4*)(b_hh + 512 + jbase);
    bhn2[0] = TWOLOG2E * bn.x; bhn2[1] = TWOLOG2E * bn.y;
    bhn2[2] = TWOLOG2E * bn.z; bhn2[3] = TWOLOG2E * bn.w;
  }

  const int len = lengths[bb + r];

  // stage att as [r][t], pre-zeroed beyond each row's length
  for (int i = tid; i < T_STEPS * 16; i += 1024) {
    const int tt = i >> 4, rr = i & 15;
    const float a = att[(size_t)tt * 512 + bb + rr];
    att_s[rr * ATT_STRIDE + tt] = (tt < lengths[bb + rr]) ? a : 0.f;
  }

  // h carry in f32 regs + f16 copy to hs0
  float hc[4];
  {
    float4 h4 = *(const float4*)(h0 + (size_t)(bb + r) * 256 + jbase);
    hc[0] = h4.x; hc[1] = h4.y; hc[2] = h4.z; hc[3] = h4.w;
    f16x4 hv; hv[0] = (f16)h4.x; hv[1] = (f16)h4.y; hv[2] = (f16)h4.z; hv[3] = (f16)h4.w;
    *(f16x4*)(&hs0[r * 264 + jbase]) = hv;
  }

  // prefetch t=0,1 (sets 0,1); running pointer starts at t=2 (distance-2)
  const size_t gb0 = (size_t)blk * 8192 + (size_t)w * 512 + (size_t)(kq * 16 + r) * 8;
  const f16* gplim = gi + gb0 + (size_t)(T_STEPS - 1) * GSTRIDE;
  const f16* gp    = gi + gb0 + 2 * (size_t)GSTRIDE;
  f16x8 q0 = *(const f16x8*)(gi + gb0);
  f16x8 q1 = *(const f16x8*)(gi + gb0 + GSTRIDE);
  f16x8 q2, q3;
  float* op = out + ((size_t)bb + r) * 256 + jbase;
  __syncthreads();

  for (int t = 0; t < T_STEPS; t += 4) {
    const f32x4 av4 = *(const f32x4*)(&att_s[r * ATT_STRIDE + t]);
    GRU_BODY(t,     hs0, hs1, q0, q2, av4[0])
    GRU_BODY(t + 1, hs1, hs0, q1, q3, av4[1])
    GRU_BODY(t + 2, hs0, hs1, q2, q0, av4[2])
    GRU_BODY(t + 3, hs1, hs0, q3, q1, av4[3])
  }
}

extern "C" void kernel_launch(void* const* d_in, const int* in_sizes, int n_in,
                              void* d_out, int out_size, void* d_ws, size_t ws_size,
                              hipStream_t stream) {
  const float* x       = (const float*)d_in[0];
  const float* att     = (const float*)d_in[1];
  const int*   lengths = (const int*)d_in[2];
  const float* h0      = (const float*)d_in[3];
  const float* w_ih    = (const float*)d_in[4];
  const float* w_hh    = (const float*)d_in[5];
  const float* b_ih    = (const float*)d_in[6];
  const float* b_hh    = (const float*)d_in[7];
  float* out = (float*)d_out;

  (void)in_sizes; (void)n_in; (void)out_size; (void)d_ws; (void)ws_size;

  hipLaunchKernelGGL(gi_kernel, dim3(400), dim3(512), 0, stream,
                     x, lengths, w_ih, b_ih, b_hh, (f16*)out);
  hipLaunchKernelGGL(gru_kernel, dim3(32), dim3(1024), 0, stream,
                     att, lengths, h0, w_hh, b_hh, out);
}

// Round 13
// 276.887 us; speedup vs baseline: 1.1138x; 1.1138x over previous
//
#include <hip/hip_runtime.h>
#include <hip/hip_fp16.h>
#include <stdint.h>

typedef _Float16 f16;
typedef _Float16 f16x4 __attribute__((ext_vector_type(4)));
typedef _Float16 f16x8 __attribute__((ext_vector_type(8)));
typedef float f32x4 __attribute__((ext_vector_type(4)));

#define T_STEPS 200
#define LOG2E 1.4426950408889634f
#define TWOLOG2E 2.8853900817779268f
#define GSTRIDE (512 * 512)   // f16 elements per time step of gi
#define OSTRIDE (512 * 256)   // f32 elements per time step of out
#define ATT_STRIDE 204        // floats per att_s row: 816B = 51 chunks (odd -> spread)

#define MFMA16(a,b,c) __builtin_amdgcn_mfma_f32_16x16x32_f16((a),(b),(c),0,0,0)

__device__ __forceinline__ f16x8 cvt_f16x8(const float4 lo, const float4 hi) {
  f16x8 f;
  f[0]=(f16)lo.x; f[1]=(f16)lo.y; f[2]=(f16)lo.z; f[3]=(f16)lo.w;
  f[4]=(f16)hi.x; f[5]=(f16)hi.y; f[6]=(f16)hi.z; f[7]=(f16)hi.w;
  return f;
}
__device__ __forceinline__ f16x4 cvt_f16x4v(const f32x4 v) {
  f16x4 f; f[0]=(f16)v[0]; f[1]=(f16)v[1]; f[2]=(f16)v[2]; f[3]=(f16)v[3]; return f;
}

// ---------------------------------------------------------------------------
// Kernel 1: gi stored f16 aliased into d_out, permuted so each gru thread
// reads ONE contiguous 16B chunk (8 f16: [gr e0..3, gn e0..3]) per step:
//   chunk addr (f16) = ((t*32 + blk)*16 + wv)*512 + (kq*16 + r)*8 + gate*4
// where blk = b>>4, r = b&15, wv = j>>4, kq = (j>>2)&3, e = j&3.
//   gr pre-scaled by -log2e (sigmoid), gn pre-scaled by 2*log2e (tanh).
// W_ih rows: r gate = [0,256), n gate = [512,768).
// ---------------------------------------------------------------------------
__global__ __launch_bounds__(512, 2) void gi_kernel(
    const float* __restrict__ x,
    const int*   __restrict__ lengths,
    const float* __restrict__ w_ih,
    const float* __restrict__ b_ih,
    const float* __restrict__ b_hh,
    f16*         __restrict__ gi)
{
  const int m0 = blockIdx.x * 256;
  const int t  = m0 >> 9;
  const int bhalf = m0 & 511;          // 0 or 256
  if (t >= lengths[bhalf]) return;     // whole half-slice dead

  int nlive = 0;
  while (nlive < 16 && t < lengths[bhalf + nlive * 16]) ++nlive;

  __shared__ __align__(16) f16 xs[2][16 * 264];

  const int tid  = threadIdx.x;
  const int wave = tid >> 6;
  const int lane = tid & 63;
  const int cl   = lane & 15;
  const int kq   = lane >> 4;
  const int kk   = kq * 8;
  const float kscale = (wave < 4) ? -LOG2E : TWOLOG2E;

  f16x8 wf[4][8];
  float bias[4][4];
#pragma unroll
  for (int ct = 0; ct < 4; ++ct) {
    const int crow = wave * 64 + ct * 16 + cl;
    const int srow = (wave < 4) ? crow : (256 + crow);   // n gate rows 512+
    const float* p = w_ih + (size_t)srow * 256 + kk;
#pragma unroll
    for (int kt = 0; kt < 8; ++kt)
      wf[ct][kt] = cvt_f16x8(*(const float4*)(p + kt * 32),
                             *(const float4*)(p + kt * 32 + 4));
    const int cb = wave * 64 + ct * 16 + kq * 4;
    if (wave < 4) {
      float4 bi = *(const float4*)(b_ih + cb);
      float4 bh = *(const float4*)(b_hh + cb);
      bias[ct][0] = bi.x + bh.x; bias[ct][1] = bi.y + bh.y;
      bias[ct][2] = bi.z + bh.z; bias[ct][3] = bi.w + bh.w;
    } else {
      float4 bi = *(const float4*)(b_ih + 256 + cb);
      bias[ct][0] = bi.x; bias[ct][1] = bi.y;
      bias[ct][2] = bi.z; bias[ct][3] = bi.w;
    }
  }

  const int wv0   = (wave & 3) * 4;          // + ct
  const int gate4 = (wave >= 4) ? 4 : 0;

  f32x4 g[2];
#pragma unroll
  for (int i = 0; i < 2; ++i) {
    int q = i * 512 + tid; int r = q >> 6; int kc = (q & 63) * 4;
    g[i] = __builtin_nontemporal_load(
        (const f32x4*)(x + (size_t)(m0 + r) * 256 + kc));
  }
#pragma unroll
  for (int i = 0; i < 2; ++i) {
    int q = i * 512 + tid; int r = q >> 6; int kc = (q & 63) * 4;
    *(f16x4*)(&xs[0][r * 264 + kc]) = cvt_f16x4v(g[i]);
  }
  __syncthreads();

  for (int ms = 0; ms < nlive; ++ms) {
    const int buf = ms & 1;
    const bool more = (ms + 1) < nlive;
    if (more) {
#pragma unroll
      for (int i = 0; i < 2; ++i) {
        int q = i * 512 + tid; int r = q >> 6; int kc = (q & 63) * 4;
        g[i] = __builtin_nontemporal_load(
            (const f32x4*)(x + (size_t)(m0 + (ms + 1) * 16 + r) * 256 + kc));
      }
    }
    f32x4 acc[4];
#pragma unroll
    for (int ct = 0; ct < 4; ++ct) acc[ct] = (f32x4){0.f, 0.f, 0.f, 0.f};
#pragma unroll
    for (int kt = 0; kt < 8; ++kt) {
      f16x8 bx = *(const f16x8*)(&xs[buf][cl * 264 + kt * 32 + kk]);
#pragma unroll
      for (int ct = 0; ct < 4; ++ct)
        acc[ct] = MFMA16(wf[ct][kt], bx, acc[ct]);
    }
    const int blk = (bhalf >> 4) + ms;     // batch-block of 16 rows
    const size_t base = ((size_t)t * 32 + blk) * 8192
                      + (size_t)(kq * 16 + cl) * 8 + gate4;
#pragma unroll
    for (int ct = 0; ct < 4; ++ct) {
      f16x4 v;
#pragma unroll
      for (int e = 0; e < 4; ++e)
        v[e] = (f16)(kscale * (acc[ct][e] + bias[ct][e]));
      *(f16x4*)(gi + base + (size_t)(wv0 + ct) * 512) = v;
    }
    if (more) {
#pragma unroll
      for (int i = 0; i < 2; ++i) {
        int q = i * 512 + tid; int r = q >> 6; int kc = (q & 63) * 4;
        *(f16x4*)(&xs[buf ^ 1][r * 264 + kc]) = cvt_f16x4v(g[i]);
      }
    }
    __syncthreads();
  }
}

// ---------------------------------------------------------------------------
// Kernel 2: recurrence. 32 blocks x 16 rows, 16 waves (1024 thr, 4/SIMD).
// Round-10 base (232 us) + this round: ATT_STRIDE 204 (att reads were an
// 8-way bank conflict at 208), no sched_barrier after the barrier (let the
// scheduler overlap VALU across it), prefetch clamp removed via tail peel.
// GRU_BODY params: LD = issue next-step gi load, BAR = barrier at end.
// ---------------------------------------------------------------------------
#define GRU_BODY(T, HSR, HSW, Qu, Qd, AV, LD, BAR)                             \
  {                                                                            \
    if (LD) { Qd = *(const f16x8*)gp; gp += GSTRIDE; }                         \
    f32x4 ar = (f32x4){0.f,0.f,0.f,0.f}, an = ar;                              \
    _Pragma("unroll")                                                          \
    for (int kt = 0; kt < 8; ++kt) {                                           \
      f16x8 hf = *(const f16x8*)(&HSR[r * 264 + kt * 32 + kk]);                \
      ar = MFMA16(whr[kt], hf, ar);                                            \
      an = MFMA16(whn[kt], hf, an);                                            \
    }                                                                          \
    const bool live = (T) < len;                                               \
    const float Au = AV;                                                       \
    f32x4 sv; f16x4 hv;                                                        \
    _Pragma("unroll")                                                          \
    for (int e = 0; e < 4; ++e) {                                              \
      float gr  = (float)Qu[e];                                                \
      float gn  = (float)Qu[4 + e];                                            \
      float e2  = __builtin_amdgcn_exp2f(fmaf(ar[e], -LOG2E, gr));             \
      float rst = __builtin_amdgcn_rcpf(1.f + e2);                             \
      float hnv = fmaf(an[e], TWOLOG2E, bhn2[e]);                              \
      float q2  = fmaf(rst, hnv, gn);                                          \
      float en  = __builtin_amdgcn_exp2f(q2);                                  \
      float ns  = fmaf(-2.f, __builtin_amdgcn_rcpf(1.f + en), 1.f);            \
      float hy  = fmaf(Au, ns - hc[e], hc[e]);                                 \
      hc[e] = hy;                            /* att==0 past len -> frozen */   \
      sv[e] = live ? hy : 0.f;                                                 \
      hv[e] = (f16)hy;                                                         \
    }                                                                          \
    __builtin_nontemporal_store(sv, (f32x4*)op);                               \
    op += OSTRIDE;                                                             \
    *(f16x4*)(&HSW[r * 264 + jbase]) = hv;                                     \
    if (BAR) {                                                                 \
      asm volatile("s_waitcnt lgkmcnt(0)" ::: "memory");                       \
      __builtin_amdgcn_s_barrier();                                            \
    }                                                                          \
  }

__global__ __launch_bounds__(1024, 4) void gru_kernel(
    const float* __restrict__ att,
    const int*   __restrict__ lengths,
    const float* __restrict__ h0,
    const float* __restrict__ w_hh,
    const float* __restrict__ b_hh,
    float*       __restrict__ out)
{
  const f16* gi = (const f16*)out;   // aliased precomputed gi (permuted chunks)
  const int blk  = blockIdx.x;
  const int bb   = blk * 16;
  const int tid  = threadIdx.x;
  const int w    = tid >> 6;         // 0..15
  const int lane = tid & 63;
  const int r    = lane & 15;        // thread's batch row (local)
  const int kq   = lane >> 4;
  const int kk   = kq * 8;
  const int jbase = w * 16 + kq * 4; // thread's 4 output cols

  __shared__ __align__(16) f16   hs0[16 * 264];
  __shared__ __align__(16) f16   hs1[16 * 264];
  __shared__ __align__(16) float att_s[16 * ATT_STRIDE];   // [r][t], stride 204

  // resident W_hh A-frags: wave owns rows j = w*16+r (r-gate), 512+w*16+r (n)
  f16x8 whr[8], whn[8];
  {
    const int jrow = w * 16 + r;
    const float* pr = w_hh + (size_t)jrow * 256 + kk;
    const float* pn = w_hh + (size_t)(512 + jrow) * 256 + kk;
#pragma unroll
    for (int kt = 0; kt < 8; ++kt) {
      whr[kt] = cvt_f16x8(*(const float4*)(pr + kt * 32),
                          *(const float4*)(pr + kt * 32 + 4));
      whn[kt] = cvt_f16x8(*(const float4*)(pn + kt * 32),
                          *(const float4*)(pn + kt * 32 + 4));
    }
  }

  float bhn2[4];
  {
    float4 bn = *(const float4*)(b_hh + 512 + jbase);
    bhn2[0] = TWOLOG2E * bn.x; bhn2[1] = TWOLOG2E * bn.y;
    bhn2[2] = TWOLOG2E * bn.z; bhn2[3] = TWOLOG2E * bn.w;
  }

  const int len = lengths[bb + r];

  // stage att as [r][t], pre-zeroed beyond each row's length
  for (int i = tid; i < T_STEPS * 16; i += 1024) {
    const int tt = i >> 4, rr = i & 15;
    const float a = att[(size_t)tt * 512 + bb + rr];
    att_s[rr * ATT_STRIDE + tt] = (tt < lengths[bb + rr]) ? a : 0.f;
  }

  // h carry in f32 regs + f16 copy to hs0
  float hc[4];
  {
    float4 h4 = *(const float4*)(h0 + (size_t)(bb + r) * 256 + jbase);
    hc[0] = h4.x; hc[1] = h4.y; hc[2] = h4.z; hc[3] = h4.w;
    f16x4 hv; hv[0] = (f16)h4.x; hv[1] = (f16)h4.y; hv[2] = (f16)h4.z; hv[3] = (f16)h4.w;
    *(f16x4*)(&hs0[r * 264 + jbase]) = hv;
  }

  // prefetch t=0 (set A); running pointer at t=1 (distance-1)
  const size_t gb0 = (size_t)blk * 8192 + (size_t)w * 512 + (size_t)(kq * 16 + r) * 8;
  const f16* gp = gi + gb0 + (size_t)GSTRIDE;
  f16x8 qA = *(const f16x8*)(gi + gb0);
  f16x8 qB;
  float* op = out + ((size_t)bb + r) * 256 + jbase;
  __syncthreads();

  // main loop: bodies 0..195 (all prefetches t+1 <= 196 in-bounds)
  for (int t = 0; t < 196; t += 2) {
    const float2 av2 = *(const float2*)(&att_s[r * ATT_STRIDE + t]);
    GRU_BODY(t,     hs0, hs1, qA, qB, av2.x, 1, 1)
    GRU_BODY(t + 1, hs1, hs0, qB, qA, av2.y, 1, 1)
  }
  // tail: bodies 196..199 (prefetches 197,198,199; body 199 no load/barrier)
  {
    const float2 avA = *(const float2*)(&att_s[r * ATT_STRIDE + 196]);
    GRU_BODY(196, hs0, hs1, qA, qB, avA.x, 1, 1)
    GRU_BODY(197, hs1, hs0, qB, qA, avA.y, 1, 1)
    const float2 avB = *(const float2*)(&att_s[r * ATT_STRIDE + 198]);
    GRU_BODY(198, hs0, hs1, qA, qB, avB.x, 1, 1)
    GRU_BODY(199, hs1, hs0, qB, qA, avB.y, 0, 0)
  }
}

extern "C" void kernel_launch(void* const* d_in, const int* in_sizes, int n_in,
                              void* d_out, int out_size, void* d_ws, size_t ws_size,
                              hipStream_t stream) {
  const float* x       = (const float*)d_in[0];
  const float* att     = (const float*)d_in[1];
  const int*   lengths = (const int*)d_in[2];
  const float* h0      = (const float*)d_in[3];
  const float* w_ih    = (const float*)d_in[4];
  const float* w_hh    = (const float*)d_in[5];
  const float* b_ih    = (const float*)d_in[6];
  const float* b_hh    = (const float*)d_in[7];
  float* out = (float*)d_out;

  (void)in_sizes; (void)n_in; (void)out_size; (void)d_ws; (void)ws_size;

  hipLaunchKernelGGL(gi_kernel, dim3(400), dim3(512), 0, stream,
                     x, lengths, w_ih, b_ih, b_hh, (f16*)out);
  hipLaunchKernelGGL(gru_kernel, dim3(32), dim3(1024), 0, stream,
                     att, lengths, h0, w_hh, b_hh, out);
}